// Round 2
// baseline (2778.911 us; speedup 1.0000x reference)
//
#include <hip/hip_runtime.h>
#include <math.h>

#define H_COEF 0.1f
#define LN_EPS 1e-5

// LDS staging swizzle for 16-channel x 256-edge tiles.
// word = c*256 + (el ^ ((c>>2)<<3)): write phase (fixed c, lanes=el) is a
// lane permutation -> 2-way max; read phase (4 lanes share el, c differs in
// bits 2-3) XOR-spreads those lanes across banks -> 2-way max.
__device__ __forceinline__ int lds_idx16(int c, int el) {
  return (c << 8) + (el ^ ((c >> 2) << 3));
}

// ---------------------------------------------------------------------------
// Block-level (sum, sumsq) reduction -> atomicAdd(double) to global stat[2].
// ---------------------------------------------------------------------------
__device__ __forceinline__ void stat_reduce(float s, float ss, double* stat) {
#pragma unroll
  for (int off = 32; off > 0; off >>= 1) {
    s += __shfl_down(s, off);
    ss += __shfl_down(ss, off);
  }
  __shared__ float bs[8], bss[8];
  const int wid = threadIdx.x >> 6;
  const int lane = threadIdx.x & 63;
  if (lane == 0) { bs[wid] = s; bss[wid] = ss; }
  __syncthreads();
  if (threadIdx.x == 0) {
    float S = 0.f, SS = 0.f;
    const int nw = blockDim.x >> 6;
    for (int w = 0; w < nw; w++) { S += bs[w]; SS += bss[w]; }
    atomicAdd(stat, (double)S);
    atomicAdd(stat + 1, (double)SS);
  }
}

// ---------------------------------------------------------------------------
// Weight prep: transposed (and pre-combined) copies, [k][c] layout.
// ---------------------------------------------------------------------------
__global__ __launch_bounds__(256) void prep_weights_kernel(
    const float* __restrict__ KE1, const float* __restrict__ KN,
    const float* __restrict__ KNopen, const float* __restrict__ KNclose,
    float* __restrict__ WUT, float* __restrict__ WVT, float* __restrict__ WNaT,
    float* __restrict__ WNbT, float* __restrict__ WNcT,
    float* __restrict__ WNopT, float* __restrict__ WNclT, int nlayer) {
  const int idx = blockIdx.x * blockDim.x + threadIdx.x;
  const int total = nlayer * 4096;
  if (idx < total) {
    const int l = idx >> 12;
    const int r = idx & 4095;
    const int k = r >> 6;
    const int c = r & 63;
    const float a = KE1[(size_t)l * 12288 + c * 192 + k];
    const float g = KE1[(size_t)l * 12288 + c * 192 + 128 + k];
    WUT[idx] = 0.5f * a + g;
    WVT[idx] = 0.5f * a - g;
    WNaT[idx] = KN[(size_t)l * 12288 + c * 192 + k];
    WNbT[idx] = KN[(size_t)l * 12288 + c * 192 + 64 + k];
    WNcT[idx] = KN[(size_t)l * 12288 + c * 192 + 128 + k];
  }
  if (idx < 4096) {
    const int k = idx >> 6;
    const int c = idx & 63;
    WNclT[idx] = KNclose[c * 64 + k];
    if (k < 16) WNopT[k * 64 + c] = KNopen[c * 16 + k];
  }
}

// ---------------------------------------------------------------------------
// CSR construction (per launch; indices are fixed inputs).
// ---------------------------------------------------------------------------
__global__ __launch_bounds__(256) void hist_kernel(
    const int* __restrict__ iInd, const int* __restrict__ jInd,
    int* __restrict__ cnt_i, int* __restrict__ cnt_j, int E) {
  const int e = blockIdx.x * blockDim.x + threadIdx.x;
  if (e < E) {
    atomicAdd(&cnt_i[iInd[e]], 1);
    atomicAdd(&cnt_j[jInd[e]], 1);
  }
}

// Packed scan: cnt_i in low 32 bits, cnt_j in high 32 bits (single pass).
__global__ __launch_bounds__(1024) void scan_kernel(
    const int* __restrict__ cnt_i, const int* __restrict__ cnt_j,
    int* __restrict__ rowptr_i, int* __restrict__ cursor_i,
    int* __restrict__ rowptr_j, int* __restrict__ cursor_j, int N) {
  __shared__ unsigned long long carry;
  __shared__ unsigned long long tmp[1024];
  if (threadIdx.x == 0) carry = 0ull;
  __syncthreads();
  for (int base = 0; base < N; base += 1024) {
    const int idx = base + threadIdx.x;
    unsigned long long v = 0ull;
    if (idx < N)
      v = (unsigned long long)(unsigned)cnt_i[idx] |
          ((unsigned long long)(unsigned)cnt_j[idx] << 32);
    tmp[threadIdx.x] = v;
    unsigned long long acc = v;
    __syncthreads();
    for (int off = 1; off < 1024; off <<= 1) {
      const unsigned long long add =
          (threadIdx.x >= (unsigned)off) ? tmp[threadIdx.x - off] : 0ull;
      __syncthreads();
      acc += add;
      tmp[threadIdx.x] = acc;
      __syncthreads();
    }
    const unsigned long long excl = acc - v + carry;
    if (idx < N) {
      const int lo = (int)(excl & 0xffffffffull);
      const int hi = (int)(excl >> 32);
      rowptr_i[idx] = lo;
      cursor_i[idx] = lo;
      rowptr_j[idx] = hi;
      cursor_j[idx] = hi;
    }
    __syncthreads();
    if (threadIdx.x == 1023) carry += tmp[1023];
    __syncthreads();
  }
  if (threadIdx.x == 0) {
    rowptr_i[N] = (int)(carry & 0xffffffffull);
    rowptr_j[N] = (int)(carry >> 32);
  }
}

__global__ __launch_bounds__(256) void fill_kernel(
    const int* __restrict__ iInd, const int* __restrict__ jInd,
    int* __restrict__ cursor_i, int* __restrict__ cursor_j,
    int* __restrict__ perm_i, int* __restrict__ perm_j, int E) {
  const int e = blockIdx.x * blockDim.x + threadIdx.x;
  if (e < E) {
    perm_i[atomicAdd(&cursor_i[iInd[e]], 1)] = e;
    perm_j[atomicAdd(&cursor_j[jInd[e]], 1)] = e;
  }
}

// ---------------------------------------------------------------------------
// Node open fused with layer-0 U/V: one wave per node, lane = channel c.
// ---------------------------------------------------------------------------
__global__ __launch_bounds__(256) void open_node_uv_kernel(
    const float* __restrict__ WNopT, const float* __restrict__ xn_in,
    const float* __restrict__ WUT0, const float* __restrict__ WVT0,
    float* __restrict__ xn_node, float* __restrict__ U, float* __restrict__ V,
    int N) {
  const int n = blockIdx.x * 4 + (threadIdx.x >> 6);
  const int c = threadIdx.x & 63;
  if (n >= N) return;
  const float xv = (c < 16) ? xn_in[(size_t)c * N + n] : 0.f;
  float acc = 0.f;
#pragma unroll
  for (int k = 0; k < 16; k++) acc += WNopT[k * 64 + c] * __shfl(xv, k);
  xn_node[(size_t)n * 64 + c] = acc;
  float ua = 0.f, va = 0.f;
#pragma unroll
  for (int k = 0; k < 64; k++) {
    const float xk = __shfl(acc, k);
    ua += WUT0[k * 64 + c] * xk;
    va += WVT0[k * 64 + c] * xk;
  }
  U[(size_t)n * 64 + c] = ua;
  V[(size_t)n * 64 + c] = va;
}

// ---------------------------------------------------------------------------
// edge1: y[e][:] = U[i(e)][:] + V[j(e)][:] + B1 @ xe[:,e];  stats of y.
// FIRST layer additionally computes xe = KEopen @ xe_in on the fly and
// writes it (open_kernel fused away).
// Matmul is c-tiled (4 x 16 outputs, rolled loop) -> ~8 KB body.
// Output staged per 16-ch tile through 16 KB LDS (full-line global writes).
// ---------------------------------------------------------------------------
template <bool FIRST>
__global__ __launch_bounds__(256) void edge1_kernel(
    const float* __restrict__ KE1_l, const float* __restrict__ KEopen,
    const float* __restrict__ xe_in, float* __restrict__ xe,
    const float* __restrict__ U, const float* __restrict__ V,
    const int* __restrict__ iInd, const int* __restrict__ jInd,
    float* __restrict__ y, double* __restrict__ stat, int E) {
  __shared__ float sbuf[4096];
  const int t = threadIdx.x;
  const int base = blockIdx.x * 256;
  const int e = base + t;
  const bool full = (base + 256 <= E);
  float s = 0.f, ss = 0.f;
  float xcol[64];
  int vi = 0, vj = 0;
  if (e < E) {
    vi = iInd[e];
    vj = jInd[e];
    if (FIRST) {
      float xin[16];
#pragma unroll
      for (int k = 0; k < 16; k++) xin[k] = xe_in[(size_t)k * E + e];
#pragma unroll
      for (int cc = 0; cc < 64; cc++) {
        float a = 0.f;
#pragma unroll
        for (int k = 0; k < 16; k++) a += KEopen[cc * 16 + k] * xin[k];
        xcol[cc] = a;
        xe[(size_t)cc * E + e] = a;
      }
    } else {
#pragma unroll
      for (int k = 0; k < 64; k++) xcol[k] = xe[(size_t)k * E + e];
    }
  }
  const float4* Up = (const float4*)(U + (size_t)vi * 64);
  const float4* Vp = (const float4*)(V + (size_t)vj * 64);
  for (int cb = 0; cb < 4; cb++) {  // rolled: small I-footprint
    float acc[16];
    if (e < E) {
#pragma unroll
      for (int q = 0; q < 4; q++) {
        const float4 uq = Up[cb * 4 + q];
        const float4 vq = Vp[cb * 4 + q];
        acc[q * 4 + 0] = uq.x + vq.x;
        acc[q * 4 + 1] = uq.y + vq.y;
        acc[q * 4 + 2] = uq.z + vq.z;
        acc[q * 4 + 3] = uq.w + vq.w;
      }
#pragma unroll
      for (int cc = 0; cc < 16; cc++) {
        const float* row = KE1_l + (cb * 16 + cc) * 192 + 64;
        float a = acc[cc];
#pragma unroll
        for (int k = 0; k < 64; k++) a += row[k] * xcol[k];
        acc[cc] = a;
        s += a;
        ss += a * a;
      }
    }
    if (full) {
#pragma unroll
      for (int cc = 0; cc < 16; cc++) sbuf[lds_idx16(cc, t)] = acc[cc];
      __syncthreads();
      float4* dst = (float4*)(y + (size_t)base * 64);
#pragma unroll
      for (int it = 0; it < 4; it++) {
        const int f4 = t + it * 256;
        const int el = f4 >> 2;
        const int qq = f4 & 3;
        float4 r;
        r.x = sbuf[lds_idx16(qq * 4 + 0, el)];
        r.y = sbuf[lds_idx16(qq * 4 + 1, el)];
        r.z = sbuf[lds_idx16(qq * 4 + 2, el)];
        r.w = sbuf[lds_idx16(qq * 4 + 3, el)];
        dst[(size_t)el * 16 + cb * 4 + qq] = r;
      }
      __syncthreads();
    } else if (e < E) {
#pragma unroll
      for (int cc = 0; cc < 16; cc++)
        y[(size_t)e * 64 + cb * 16 + cc] = acc[cc];
    }
  }
  stat_reduce(s, ss, stat);
}

// ---------------------------------------------------------------------------
// edge2: t = relu(ln(y row)); y row <- KE2 @ t (in place); stats of new y.
// Direct per-row reads (rows are L2/L3-hot from edge1); c-tiled matmul;
// per-tile LDS-staged writes. In-place safety: every thread consumes its
// entire row in tile 0's matmul, and __syncthreads drains vmcnt before the
// first staged global write.
// ---------------------------------------------------------------------------
__global__ __launch_bounds__(256) void edge2_kernel(
    const float* __restrict__ W, float* __restrict__ y,
    const double* __restrict__ statIn, double* __restrict__ statOut,
    double inv_n, int E) {
  __shared__ float sbuf[4096];
  const int t = threadIdx.x;
  const int base = blockIdx.x * 256;
  const int e = base + t;
  const bool full = (base + 256 <= E);
  float s = 0.f, ss = 0.f;
  float tv[64];
  if (e < E) {
    const double m = statIn[0] * inv_n;
    const double v = statIn[1] * inv_n - m * m;
    const float fm = (float)m;
    const float finv = (float)(1.0 / sqrt(v + LN_EPS));
    const float4* yrow = (const float4*)(y + (size_t)e * 64);
#pragma unroll
    for (int q = 0; q < 16; q++) {
      const float4 r = yrow[q];
      const float* rp = (const float*)&r;
#pragma unroll
      for (int u = 0; u < 4; u++) {
        const float val = (rp[u] - fm) * finv;
        tv[q * 4 + u] = val > 0.f ? val : 0.f;
      }
    }
  }
  for (int cb = 0; cb < 4; cb++) {
    float acc[16];
    if (e < E) {
#pragma unroll
      for (int cc = 0; cc < 16; cc++) {
        const float* row = W + (cb * 16 + cc) * 64;
        float a = 0.f;
#pragma unroll
        for (int k = 0; k < 64; k++) a += row[k] * tv[k];
        acc[cc] = a;
        s += a;
        ss += a * a;
      }
    }
    if (full) {
#pragma unroll
      for (int cc = 0; cc < 16; cc++) sbuf[lds_idx16(cc, t)] = acc[cc];
      __syncthreads();
      float4* dst = (float4*)(y + (size_t)base * 64);
#pragma unroll
      for (int it = 0; it < 4; it++) {
        const int f4 = t + it * 256;
        const int el = f4 >> 2;
        const int qq = f4 & 3;
        float4 r;
        r.x = sbuf[lds_idx16(qq * 4 + 0, el)];
        r.y = sbuf[lds_idx16(qq * 4 + 1, el)];
        r.z = sbuf[lds_idx16(qq * 4 + 2, el)];
        r.w = sbuf[lds_idx16(qq * 4 + 3, el)];
        dst[(size_t)el * 16 + cb * 4 + qq] = r;
      }
      __syncthreads();
    } else if (e < E) {
#pragma unroll
      for (int cc = 0; cc < 16; cc++)
        y[(size_t)e * 64 + cb * 16 + cc] = acc[cc];
    }
  }
  stat_reduce(s, ss, statOut);
}

// ---------------------------------------------------------------------------
// edge3: t2 = relu(ln(y row));  xe col += H * (KE3 @ t2).  y unchanged.
// c-tiled matmul; per-tile strided xe read-modify-write.
// ---------------------------------------------------------------------------
__global__ __launch_bounds__(256) void edge3_kernel(
    const float* __restrict__ W, const float* __restrict__ y,
    float* __restrict__ xe, const double* __restrict__ statIn, double inv_n,
    int E) {
  const int e = blockIdx.x * blockDim.x + threadIdx.x;
  if (e >= E) return;
  const double m = statIn[0] * inv_n;
  const double v = statIn[1] * inv_n - m * m;
  const float fm = (float)m;
  const float finv = (float)(1.0 / sqrt(v + LN_EPS));
  float tv[64];
  const float4* yrow = (const float4*)(y + (size_t)e * 64);
#pragma unroll
  for (int q = 0; q < 16; q++) {
    const float4 r = yrow[q];
    const float* rp = (const float*)&r;
#pragma unroll
    for (int u = 0; u < 4; u++) {
      const float val = (rp[u] - fm) * finv;
      tv[q * 4 + u] = val > 0.f ? val : 0.f;
    }
  }
  for (int cb = 0; cb < 4; cb++) {
    float acc[16];
#pragma unroll
    for (int cc = 0; cc < 16; cc++) {
      const float* row = W + (cb * 16 + cc) * 64;
      float a = 0.f;
#pragma unroll
      for (int k = 0; k < 64; k++) a += row[k] * tv[k];
      acc[cc] = a;
    }
#pragma unroll
    for (int cc = 0; cc < 16; cc++) {
      const size_t off = (size_t)(cb * 16 + cc) * E + e;
      xe[off] += H_COEF * acc[cc];
    }
  }
}

// ---------------------------------------------------------------------------
// Edge-side close (out-of-loop): x col <- KEclose @ x col, in place.
// Same math as the old close_inplace_kernel but c-tiled (rolled cb loop).
// ---------------------------------------------------------------------------
__global__ __launch_bounds__(256) void close_edge_kernel(
    const float* __restrict__ W, float* __restrict__ x, int M) {
  const int e = blockIdx.x * blockDim.x + threadIdx.x;
  if (e >= M) return;
  float xv[64];
#pragma unroll
  for (int k = 0; k < 64; k++) xv[k] = x[(size_t)k * M + e];
  for (int cb = 0; cb < 4; cb++) {
    float acc[16];
#pragma unroll
    for (int cc = 0; cc < 16; cc++) {
      const float* row = W + (cb * 16 + cc) * 64;
      float a = 0.f;
#pragma unroll
      for (int k = 0; k < 64; k++) a += row[k] * xv[k];
      acc[cc] = a;
    }
#pragma unroll
    for (int cc = 0; cc < 16; cc++)
      x[(size_t)(cb * 16 + cc) * M + e] = acc[cc];
  }
}

// ---------------------------------------------------------------------------
// fused node update: one wave per node; lane = channel c.
// Non-final layers additionally emit next layer's U,V (uv_kernel fused).
// Final layer applies KNclose and writes xn output (close_node fused).
// ---------------------------------------------------------------------------
template <bool FINAL>
__global__ __launch_bounds__(256) void fused_node_kernel(
    const float* __restrict__ y, const int* __restrict__ rowptr_i,
    const int* __restrict__ perm_i, const int* __restrict__ rowptr_j,
    const int* __restrict__ perm_j, const float* __restrict__ WNaT,
    const float* __restrict__ WNbT, const float* __restrict__ WNcT,
    const float* __restrict__ WUTn, const float* __restrict__ WVTn,
    const float* __restrict__ WNclT, float* __restrict__ xn_node,
    float* __restrict__ U, float* __restrict__ V, float* __restrict__ xn_out,
    const double* __restrict__ statIn, double inv_n, int N) {
  const int n = blockIdx.x * 4 + (threadIdx.x >> 6);
  const int c = threadIdx.x & 63;
  if (n >= N) return;
  const double m = statIn[0] * inv_n;
  const double v = statIn[1] * inv_n - m * m;
  const float fm = (float)m;
  const float finv = (float)(1.0 / sqrt(v + LN_EPS));

  float si = 0.f;
  const int ib = rowptr_i[n], ie = rowptr_i[n + 1];
  for (int p = ib; p < ie; ++p) {
    const float val = (y[(size_t)perm_i[p] * 64 + c] - fm) * finv;
    si += val > 0.f ? val : 0.f;
  }
  float sj = 0.f;
  const int jb = rowptr_j[n], je = rowptr_j[n + 1];
  for (int p = jb; p < je; ++p) {
    const float val = (y[(size_t)perm_j[p] * 64 + c] - fm) * finv;
    sj += val > 0.f ? val : 0.f;
  }

  const float xv = xn_node[(size_t)n * 64 + c];
  const float a = 0.5f * (si + sj);
  const float d = si - sj;
  float acc = 0.f;
#pragma unroll
  for (int k = 0; k < 64; k++) {
    const float ak = __shfl(a, k);
    const float xk = __shfl(xv, k);
    const float dk = __shfl(d, k);
    acc += WNaT[k * 64 + c] * ak;
    acc += WNbT[k * 64 + c] * xk;
    acc += WNcT[k * 64 + c] * dk;
  }
  const float xn_new = xv + H_COEF * acc;
  if (FINAL) {
    float o = 0.f;
#pragma unroll
    for (int k = 0; k < 64; k++) o += WNclT[k * 64 + c] * __shfl(xn_new, k);
    xn_out[(size_t)c * N + n] = o;
  } else {
    xn_node[(size_t)n * 64 + c] = xn_new;
    float ua = 0.f, va = 0.f;
#pragma unroll
    for (int k = 0; k < 64; k++) {
      const float xk = __shfl(xn_new, k);
      ua += WUTn[k * 64 + c] * xk;
      va += WVTn[k * 64 + c] * xk;
    }
    U[(size_t)n * 64 + c] = ua;
    V[(size_t)n * 64 + c] = va;
  }
}

// ---------------------------------------------------------------------------
extern "C" void kernel_launch(void* const* d_in, const int* in_sizes, int n_in,
                              void* d_out, int out_size, void* d_ws,
                              size_t ws_size, hipStream_t stream) {
  const float* xn_in = (const float*)d_in[0];
  const float* xe_in = (const float*)d_in[1];
  const int* iInd = (const int*)d_in[2];
  const int* jInd = (const int*)d_in[3];
  const float* KNopen = (const float*)d_in[4];
  const float* KEopen = (const float*)d_in[5];
  const float* KNclose = (const float*)d_in[6];
  const float* KEclose = (const float*)d_in[7];
  const float* KE1 = (const float*)d_in[8];
  const float* KE2 = (const float*)d_in[9];
  const float* KE3 = (const float*)d_in[10];
  const float* KN = (const float*)d_in[11];

  const int N = in_sizes[0] / 16;               // 20000
  const int E = in_sizes[2];                    // 320000
  const int nlayer = in_sizes[8] / (64 * 192);  // 4

  float* out = (float*)d_out;
  float* xn_out = out;               // [64][N] feature-major (final)
  float* xe = out + (size_t)64 * N;  // [64][E] feature-major, in-place

  float* ws = (float*)d_ws;
  float* y = ws;                          // [E][64]
  float* U = y + (size_t)64 * E;          // [N][64]
  float* V = U + (size_t)64 * N;          // [N][64]
  float* xn_node = V + (size_t)64 * N;    // [N][64]
  float* WUT = xn_node + (size_t)64 * N;  // nlayer*4096 each
  float* WVT = WUT + (size_t)4096 * nlayer;
  float* WNaT = WVT + (size_t)4096 * nlayer;
  float* WNbT = WNaT + (size_t)4096 * nlayer;
  float* WNcT = WNbT + (size_t)4096 * nlayer;
  float* WNopT = WNcT + (size_t)4096 * nlayer;  // 1024
  float* WNclT = WNopT + 1024;                  // 4096
  double* stat = (double*)(WNclT + 4096);       // nlayer*4 doubles
  int* cnt_i = (int*)(stat + 4 * nlayer);
  int* cnt_j = cnt_i + N;
  int* rowptr_i = cnt_j + N;
  int* cursor_i = rowptr_i + (N + 1);
  int* rowptr_j = cursor_i + N;
  int* cursor_j = rowptr_j + (N + 1);
  int* perm_i = cursor_j + N;
  int* perm_j = perm_i + E;

  const int be = (E + 255) / 256;
  const int bw = (N + 3) / 4;  // wave-per-node kernels
  const double inv_n = 1.0 / (64.0 * (double)E);

  hipMemsetAsync(stat, 0, (size_t)nlayer * 4 * sizeof(double), stream);
  hipMemsetAsync(cnt_i, 0, (size_t)2 * N * sizeof(int), stream);

  prep_weights_kernel<<<(nlayer * 4096 + 255) / 256, 256, 0, stream>>>(
      KE1, KN, KNopen, KNclose, WUT, WVT, WNaT, WNbT, WNcT, WNopT, WNclT,
      nlayer);

  hist_kernel<<<be, 256, 0, stream>>>(iInd, jInd, cnt_i, cnt_j, E);
  scan_kernel<<<1, 1024, 0, stream>>>(cnt_i, cnt_j, rowptr_i, cursor_i,
                                      rowptr_j, cursor_j, N);
  fill_kernel<<<be, 256, 0, stream>>>(iInd, jInd, cursor_i, cursor_j, perm_i,
                                      perm_j, E);

  open_node_uv_kernel<<<bw, 256, 0, stream>>>(WNopT, xn_in, WUT, WVT, xn_node,
                                              U, V, N);

  for (int l = 0; l < nlayer; l++) {
    const float* KE1_l = KE1 + (size_t)l * 64 * 192;
    const float* KE2_l = KE2 + (size_t)l * 64 * 64;
    const float* KE3_l = KE3 + (size_t)l * 64 * 64;
    double* st1 = stat + (size_t)l * 4;
    double* st2 = st1 + 2;
    const bool last = (l == nlayer - 1);

    if (l == 0) {
      edge1_kernel<true><<<be, 256, 0, stream>>>(KE1_l, KEopen, xe_in, xe, U,
                                                 V, iInd, jInd, y, st1, E);
    } else {
      edge1_kernel<false><<<be, 256, 0, stream>>>(KE1_l, KEopen, xe_in, xe, U,
                                                  V, iInd, jInd, y, st1, E);
    }
    edge2_kernel<<<be, 256, 0, stream>>>(KE2_l, y, st1, st2, inv_n, E);
    edge3_kernel<<<be, 256, 0, stream>>>(KE3_l, y, xe, st2, inv_n, E);
    if (last) {
      fused_node_kernel<true><<<bw, 256, 0, stream>>>(
          y, rowptr_i, perm_i, rowptr_j, perm_j, WNaT + (size_t)l * 4096,
          WNbT + (size_t)l * 4096, WNcT + (size_t)l * 4096, WUT, WVT, WNclT,
          xn_node, U, V, xn_out, st2, inv_n, N);
    } else {
      fused_node_kernel<false><<<bw, 256, 0, stream>>>(
          y, rowptr_i, perm_i, rowptr_j, perm_j, WNaT + (size_t)l * 4096,
          WNbT + (size_t)l * 4096, WNcT + (size_t)l * 4096,
          WUT + (size_t)(l + 1) * 4096, WVT + (size_t)(l + 1) * 4096, WNclT,
          xn_node, U, V, xn_out, st2, inv_n, N);
    }
  }

  close_edge_kernel<<<be, 256, 0, stream>>>(KEclose, xe, E);
}

// Round 3
// 2646.992 us; speedup vs baseline: 1.0498x; 1.0498x over previous
//
#include <hip/hip_runtime.h>
#include <math.h>

#define H_COEF 0.1f
#define LN_EPS 1e-5

// LDS staging swizzle for 32-channel x 256-edge half-tiles (32 KB).
// word = lc*256 + (el ^ lc), lc in [0,32). Write phase (fixed lc, lanes=el)
// is a lane permutation -> conflict-free. Read phase measured-equivalent to
// the old proven layout: 2-way max (free).
__device__ __forceinline__ int lds_idx(int lc, int el) {
  return (lc << 8) + (el ^ lc);
}

// 4 parallel accumulator chains over k (4-way ILP vs 4-cyc FMA latency).
// Per-channel summation order (k ascending) identical to baseline.
template <int STRIDE>
__device__ __forceinline__ void mm4(const float* __restrict__ Wr,
                                    const float (&x)[64], float (&acc)[4]) {
#pragma unroll
  for (int k = 0; k < 64; k++) {
    const float xk = x[k];
    acc[0] += Wr[0 * STRIDE + k] * xk;
    acc[1] += Wr[1 * STRIDE + k] * xk;
    acc[2] += Wr[2 * STRIDE + k] * xk;
    acc[3] += Wr[3 * STRIDE + k] * xk;
  }
}

// ---------------------------------------------------------------------------
// Block-level (sum, sumsq) reduction -> atomicAdd(double) to global stat[2].
// ---------------------------------------------------------------------------
__device__ __forceinline__ void stat_reduce(float s, float ss, double* stat) {
#pragma unroll
  for (int off = 32; off > 0; off >>= 1) {
    s += __shfl_down(s, off);
    ss += __shfl_down(ss, off);
  }
  __shared__ float bs[8], bss[8];
  const int wid = threadIdx.x >> 6;
  const int lane = threadIdx.x & 63;
  if (lane == 0) { bs[wid] = s; bss[wid] = ss; }
  __syncthreads();
  if (threadIdx.x == 0) {
    float S = 0.f, SS = 0.f;
    const int nw = blockDim.x >> 6;
    for (int w = 0; w < nw; w++) { S += bs[w]; SS += bss[w]; }
    atomicAdd(stat, (double)S);
    atomicAdd(stat + 1, (double)SS);
  }
}

// ---------------------------------------------------------------------------
// Weight prep: transposed (and pre-combined) copies, [k][c] layout.
// ---------------------------------------------------------------------------
__global__ __launch_bounds__(256) void prep_weights_kernel(
    const float* __restrict__ KE1, const float* __restrict__ KN,
    const float* __restrict__ KNopen, const float* __restrict__ KNclose,
    float* __restrict__ WUT, float* __restrict__ WVT, float* __restrict__ WNaT,
    float* __restrict__ WNbT, float* __restrict__ WNcT,
    float* __restrict__ WNopT, float* __restrict__ WNclT, int nlayer) {
  const int idx = blockIdx.x * blockDim.x + threadIdx.x;
  const int total = nlayer * 4096;
  if (idx < total) {
    const int l = idx >> 12;
    const int r = idx & 4095;
    const int k = r >> 6;
    const int c = r & 63;
    const float a = KE1[(size_t)l * 12288 + c * 192 + k];
    const float g = KE1[(size_t)l * 12288 + c * 192 + 128 + k];
    WUT[idx] = 0.5f * a + g;
    WVT[idx] = 0.5f * a - g;
    WNaT[idx] = KN[(size_t)l * 12288 + c * 192 + k];
    WNbT[idx] = KN[(size_t)l * 12288 + c * 192 + 64 + k];
    WNcT[idx] = KN[(size_t)l * 12288 + c * 192 + 128 + k];
  }
  if (idx < 4096) {
    const int k = idx >> 6;
    const int c = idx & 63;
    WNclT[idx] = KNclose[c * 64 + k];
    if (k < 16) WNopT[k * 64 + c] = KNopen[c * 16 + k];
  }
}

// ---------------------------------------------------------------------------
// CSR construction (per launch; indices are fixed inputs).
// ---------------------------------------------------------------------------
__global__ __launch_bounds__(256) void hist_kernel(
    const int* __restrict__ iInd, const int* __restrict__ jInd,
    int* __restrict__ cnt_i, int* __restrict__ cnt_j, int E) {
  const int e = blockIdx.x * blockDim.x + threadIdx.x;
  if (e < E) {
    atomicAdd(&cnt_i[iInd[e]], 1);
    atomicAdd(&cnt_j[jInd[e]], 1);
  }
}

// Packed scan: cnt_i in low 32 bits, cnt_j in high 32 bits (single pass).
__global__ __launch_bounds__(1024) void scan_kernel(
    const int* __restrict__ cnt_i, const int* __restrict__ cnt_j,
    int* __restrict__ rowptr_i, int* __restrict__ cursor_i,
    int* __restrict__ rowptr_j, int* __restrict__ cursor_j, int N) {
  __shared__ unsigned long long carry;
  __shared__ unsigned long long tmp[1024];
  if (threadIdx.x == 0) carry = 0ull;
  __syncthreads();
  for (int base = 0; base < N; base += 1024) {
    const int idx = base + threadIdx.x;
    unsigned long long v = 0ull;
    if (idx < N)
      v = (unsigned long long)(unsigned)cnt_i[idx] |
          ((unsigned long long)(unsigned)cnt_j[idx] << 32);
    tmp[threadIdx.x] = v;
    unsigned long long acc = v;
    __syncthreads();
    for (int off = 1; off < 1024; off <<= 1) {
      const unsigned long long add =
          (threadIdx.x >= (unsigned)off) ? tmp[threadIdx.x - off] : 0ull;
      __syncthreads();
      acc += add;
      tmp[threadIdx.x] = acc;
      __syncthreads();
    }
    const unsigned long long excl = acc - v + carry;
    if (idx < N) {
      const int lo = (int)(excl & 0xffffffffull);
      const int hi = (int)(excl >> 32);
      rowptr_i[idx] = lo;
      cursor_i[idx] = lo;
      rowptr_j[idx] = hi;
      cursor_j[idx] = hi;
    }
    __syncthreads();
    if (threadIdx.x == 1023) carry += tmp[1023];
    __syncthreads();
  }
  if (threadIdx.x == 0) {
    rowptr_i[N] = (int)(carry & 0xffffffffull);
    rowptr_j[N] = (int)(carry >> 32);
  }
}

__global__ __launch_bounds__(256) void fill_kernel(
    const int* __restrict__ iInd, const int* __restrict__ jInd,
    int* __restrict__ cursor_i, int* __restrict__ cursor_j,
    int* __restrict__ perm_i, int* __restrict__ perm_j, int E) {
  const int e = blockIdx.x * blockDim.x + threadIdx.x;
  if (e < E) {
    perm_i[atomicAdd(&cursor_i[iInd[e]], 1)] = e;
    perm_j[atomicAdd(&cursor_j[jInd[e]], 1)] = e;
  }
}

// ---------------------------------------------------------------------------
// Node open fused with layer-0 U/V: one wave per node, lane = channel c.
// ---------------------------------------------------------------------------
__global__ __launch_bounds__(256) void open_node_uv_kernel(
    const float* __restrict__ WNopT, const float* __restrict__ xn_in,
    const float* __restrict__ WUT0, const float* __restrict__ WVT0,
    float* __restrict__ xn_node, float* __restrict__ U, float* __restrict__ V,
    int N) {
  const int n = blockIdx.x * 4 + (threadIdx.x >> 6);
  const int c = threadIdx.x & 63;
  if (n >= N) return;
  const float xv = (c < 16) ? xn_in[(size_t)c * N + n] : 0.f;
  float acc = 0.f;
#pragma unroll
  for (int k = 0; k < 16; k++) acc += WNopT[k * 64 + c] * __shfl(xv, k);
  xn_node[(size_t)n * 64 + c] = acc;
  float ua = 0.f, va = 0.f;
#pragma unroll
  for (int k = 0; k < 64; k++) {
    const float xk = __shfl(acc, k);
    ua += WUT0[k * 64 + c] * xk;
    va += WVT0[k * 64 + c] * xk;
  }
  U[(size_t)n * 64 + c] = ua;
  V[(size_t)n * 64 + c] = va;
}

// ---------------------------------------------------------------------------
// edge1: y[e][:] = U[i(e)][:] + V[j(e)][:] + B1 @ xe_row(e);  stats of y.
// xe is EDGE-major [E][64] -> row reads are float4-contiguous.
// FIRST layer computes xe = KEopen @ xe_in on the fly (xe_in is [16][E]
// feature-major, strided once) and writes the edge-major xe rows.
// Full unroll, no barriers inside compute; output staged in two 32-channel
// halves through 32 KB LDS (complete 128B lines per phase -> no L2 write
// amplification).
// ---------------------------------------------------------------------------
template <bool FIRST>
__global__ __launch_bounds__(256) void edge1_kernel(
    const float* __restrict__ KE1_l, const float* __restrict__ KEopen,
    const float* __restrict__ xe_in, float* __restrict__ xe,
    const float* __restrict__ U, const float* __restrict__ V,
    const int* __restrict__ iInd, const int* __restrict__ jInd,
    float* __restrict__ y, double* __restrict__ stat, int E) {
  __shared__ float sbuf[8192];
  const int t = threadIdx.x;
  const int base = blockIdx.x * 256;
  const int e = base + t;
  const bool full = (base + 256 <= E);
  float s = 0.f, ss = 0.f;
  float xcol[64];

  if (e < E) {
    if (FIRST) {
      float xin[16];
#pragma unroll
      for (int k = 0; k < 16; k++) xin[k] = xe_in[(size_t)k * E + e];
#pragma unroll
      for (int cc = 0; cc < 64; cc++) {
        float a = 0.f;
#pragma unroll
        for (int k = 0; k < 16; k++) a += KEopen[cc * 16 + k] * xin[k];
        xcol[cc] = a;
      }
    } else {
      const float4* xr = (const float4*)(xe + (size_t)e * 64);
#pragma unroll
      for (int q = 0; q < 16; q++) {
        const float4 r = xr[q];
        xcol[q * 4 + 0] = r.x;
        xcol[q * 4 + 1] = r.y;
        xcol[q * 4 + 2] = r.z;
        xcol[q * 4 + 3] = r.w;
      }
    }
  }

  if (full) {
    const int vi = iInd[e];
    const int vj = jInd[e];
    const float4* Up = (const float4*)(U + (size_t)vi * 64);
    const float4* Vp = (const float4*)(V + (size_t)vj * 64);
    float4* ydst = (float4*)(y + (size_t)base * 64);
#pragma unroll
    for (int h = 0; h < 2; h++) {
#pragma unroll
      for (int g = 0; g < 8; g++) {
        const int cg = h * 8 + g;
        const float4 uq = Up[cg];
        const float4 vq = Vp[cg];
        float acc[4] = {uq.x + vq.x, uq.y + vq.y, uq.z + vq.z, uq.w + vq.w};
        mm4<192>(KE1_l + cg * 4 * 192 + 64, xcol, acc);
#pragma unroll
        for (int u = 0; u < 4; u++) {
          s += acc[u];
          ss += acc[u] * acc[u];
          sbuf[lds_idx(g * 4 + u, t)] = acc[u];
        }
      }
      __syncthreads();
#pragma unroll
      for (int it = 0; it < 8; it++) {
        const int f4 = t + it * 256;
        const int el = f4 >> 3;
        const int qq = f4 & 7;
        float4 r;
        r.x = sbuf[lds_idx(qq * 4 + 0, el)];
        r.y = sbuf[lds_idx(qq * 4 + 1, el)];
        r.z = sbuf[lds_idx(qq * 4 + 2, el)];
        r.w = sbuf[lds_idx(qq * 4 + 3, el)];
        ydst[el * 16 + h * 8 + qq] = r;
      }
      __syncthreads();
    }
    if (FIRST) {  // stage the freshly-opened xe rows out (edge-major)
      float4* xdst = (float4*)(xe + (size_t)base * 64);
#pragma unroll
      for (int h = 0; h < 2; h++) {
#pragma unroll
        for (int lc = 0; lc < 32; lc++) sbuf[lds_idx(lc, t)] = xcol[h * 32 + lc];
        __syncthreads();
#pragma unroll
        for (int it = 0; it < 8; it++) {
          const int f4 = t + it * 256;
          const int el = f4 >> 3;
          const int qq = f4 & 7;
          float4 r;
          r.x = sbuf[lds_idx(qq * 4 + 0, el)];
          r.y = sbuf[lds_idx(qq * 4 + 1, el)];
          r.z = sbuf[lds_idx(qq * 4 + 2, el)];
          r.w = sbuf[lds_idx(qq * 4 + 3, el)];
          xdst[el * 16 + h * 8 + qq] = r;
        }
        __syncthreads();
      }
    }
  } else if (e < E) {  // tail block: direct row writes
    const int vi = iInd[e];
    const int vj = jInd[e];
    const float4* Up = (const float4*)(U + (size_t)vi * 64);
    const float4* Vp = (const float4*)(V + (size_t)vj * 64);
#pragma unroll
    for (int cg = 0; cg < 16; cg++) {
      const float4 uq = Up[cg];
      const float4 vq = Vp[cg];
      float acc[4] = {uq.x + vq.x, uq.y + vq.y, uq.z + vq.z, uq.w + vq.w};
      mm4<192>(KE1_l + cg * 4 * 192 + 64, xcol, acc);
#pragma unroll
      for (int u = 0; u < 4; u++) {
        s += acc[u];
        ss += acc[u] * acc[u];
        y[(size_t)e * 64 + cg * 4 + u] = acc[u];
      }
    }
    if (FIRST) {
#pragma unroll
      for (int cc = 0; cc < 64; cc++) xe[(size_t)e * 64 + cc] = xcol[cc];
    }
  }
  stat_reduce(s, ss, stat);
}

// ---------------------------------------------------------------------------
// edge2: t = relu(ln(y row)); y row <- KE2 @ t (in place); stats of new y.
// Whole row consumed into regs up front -> in-place safe; two-half staging.
// ---------------------------------------------------------------------------
__global__ __launch_bounds__(256) void edge2_kernel(
    const float* __restrict__ W, float* __restrict__ y,
    const double* __restrict__ statIn, double* __restrict__ statOut,
    double inv_n, int E) {
  __shared__ float sbuf[8192];
  const int t = threadIdx.x;
  const int base = blockIdx.x * 256;
  const int e = base + t;
  const bool full = (base + 256 <= E);
  float s = 0.f, ss = 0.f;
  float tv[64];
  if (e < E) {
    const double m = statIn[0] * inv_n;
    const double v = statIn[1] * inv_n - m * m;
    const float fm = (float)m;
    const float finv = (float)(1.0 / sqrt(v + LN_EPS));
    const float4* yrow = (const float4*)(y + (size_t)e * 64);
#pragma unroll
    for (int q = 0; q < 16; q++) {
      const float4 r = yrow[q];
      const float* rp = (const float*)&r;
#pragma unroll
      for (int u = 0; u < 4; u++) {
        const float val = (rp[u] - fm) * finv;
        tv[q * 4 + u] = val > 0.f ? val : 0.f;
      }
    }
  }
  if (full) {
    float4* ydst = (float4*)(y + (size_t)base * 64);
#pragma unroll
    for (int h = 0; h < 2; h++) {
#pragma unroll
      for (int g = 0; g < 8; g++) {
        const int cg = h * 8 + g;
        float acc[4] = {0.f, 0.f, 0.f, 0.f};
        mm4<64>(W + cg * 4 * 64, tv, acc);
#pragma unroll
        for (int u = 0; u < 4; u++) {
          s += acc[u];
          ss += acc[u] * acc[u];
          sbuf[lds_idx(g * 4 + u, t)] = acc[u];
        }
      }
      __syncthreads();
#pragma unroll
      for (int it = 0; it < 8; it++) {
        const int f4 = t + it * 256;
        const int el = f4 >> 3;
        const int qq = f4 & 7;
        float4 r;
        r.x = sbuf[lds_idx(qq * 4 + 0, el)];
        r.y = sbuf[lds_idx(qq * 4 + 1, el)];
        r.z = sbuf[lds_idx(qq * 4 + 2, el)];
        r.w = sbuf[lds_idx(qq * 4 + 3, el)];
        ydst[el * 16 + h * 8 + qq] = r;
      }
      __syncthreads();
    }
  } else if (e < E) {
#pragma unroll
    for (int cg = 0; cg < 16; cg++) {
      float acc[4] = {0.f, 0.f, 0.f, 0.f};
      mm4<64>(W + cg * 4 * 64, tv, acc);
#pragma unroll
      for (int u = 0; u < 4; u++) {
        s += acc[u];
        ss += acc[u] * acc[u];
        y[(size_t)e * 64 + cg * 4 + u] = acc[u];
      }
    }
  }
  stat_reduce(s, ss, statOut);
}

// ---------------------------------------------------------------------------
// edge3: t2 = relu(ln(y row));  xe row += H * (KE3 @ t2).  y unchanged.
// xe edge-major -> the RMW is 16+16 contiguous float4s (was 128 strided).
// ---------------------------------------------------------------------------
__global__ __launch_bounds__(256) void edge3_kernel(
    const float* __restrict__ W, const float* __restrict__ y,
    float* __restrict__ xe, const double* __restrict__ statIn, double inv_n,
    int E) {
  const int e = blockIdx.x * blockDim.x + threadIdx.x;
  if (e >= E) return;
  const double m = statIn[0] * inv_n;
  const double v = statIn[1] * inv_n - m * m;
  const float fm = (float)m;
  const float finv = (float)(1.0 / sqrt(v + LN_EPS));
  float tv[64];
  const float4* yrow = (const float4*)(y + (size_t)e * 64);
#pragma unroll
  for (int q = 0; q < 16; q++) {
    const float4 r = yrow[q];
    const float* rp = (const float*)&r;
#pragma unroll
    for (int u = 0; u < 4; u++) {
      const float val = (rp[u] - fm) * finv;
      tv[q * 4 + u] = val > 0.f ? val : 0.f;
    }
  }
  float4* xrow = (float4*)(xe + (size_t)e * 64);
  float4 xr[16];
#pragma unroll
  for (int q = 0; q < 16; q++) xr[q] = xrow[q];
#pragma unroll
  for (int cg = 0; cg < 16; cg++) {
    float acc[4] = {0.f, 0.f, 0.f, 0.f};
    mm4<64>(W + cg * 4 * 64, tv, acc);
    xr[cg].x += H_COEF * acc[0];
    xr[cg].y += H_COEF * acc[1];
    xr[cg].z += H_COEF * acc[2];
    xr[cg].w += H_COEF * acc[3];
  }
#pragma unroll
  for (int q = 0; q < 16; q++) xrow[q] = xr[q];
}

// ---------------------------------------------------------------------------
// Edge close (out-of-loop): read xe row (edge-major), apply KEclose, write
// FEATURE-major [64][E] into scratch (y buffer, dead by now). The launcher
// then memcpys scratch -> d_out xe region.
// ---------------------------------------------------------------------------
__global__ __launch_bounds__(256) void close_edge_kernel(
    const float* __restrict__ W, const float* __restrict__ xe,
    float* __restrict__ outf, int E) {
  const int e = blockIdx.x * blockDim.x + threadIdx.x;
  if (e >= E) return;
  float xv[64];
  const float4* xr = (const float4*)(xe + (size_t)e * 64);
#pragma unroll
  for (int q = 0; q < 16; q++) {
    const float4 r = xr[q];
    xv[q * 4 + 0] = r.x;
    xv[q * 4 + 1] = r.y;
    xv[q * 4 + 2] = r.z;
    xv[q * 4 + 3] = r.w;
  }
#pragma unroll
  for (int cg = 0; cg < 16; cg++) {
    float acc[4] = {0.f, 0.f, 0.f, 0.f};
    mm4<64>(W + cg * 4 * 64, xv, acc);
#pragma unroll
    for (int u = 0; u < 4; u++)
      outf[(size_t)(cg * 4 + u) * E + e] = acc[u];
  }
}

// ---------------------------------------------------------------------------
// fused node update: one wave per node; lane = channel c.
// Non-final layers additionally emit next layer's U,V (uv fused).
// Final layer applies KNclose and writes xn output (close_node fused).
// ---------------------------------------------------------------------------
template <bool FINAL>
__global__ __launch_bounds__(256) void fused_node_kernel(
    const float* __restrict__ y, const int* __restrict__ rowptr_i,
    const int* __restrict__ perm_i, const int* __restrict__ rowptr_j,
    const int* __restrict__ perm_j, const float* __restrict__ WNaT,
    const float* __restrict__ WNbT, const float* __restrict__ WNcT,
    const float* __restrict__ WUTn, const float* __restrict__ WVTn,
    const float* __restrict__ WNclT, float* __restrict__ xn_node,
    float* __restrict__ U, float* __restrict__ V, float* __restrict__ xn_out,
    const double* __restrict__ statIn, double inv_n, int N) {
  const int n = blockIdx.x * 4 + (threadIdx.x >> 6);
  const int c = threadIdx.x & 63;
  if (n >= N) return;
  const double m = statIn[0] * inv_n;
  const double v = statIn[1] * inv_n - m * m;
  const float fm = (float)m;
  const float finv = (float)(1.0 / sqrt(v + LN_EPS));

  float si = 0.f;
  const int ib = rowptr_i[n], ie = rowptr_i[n + 1];
  for (int p = ib; p < ie; ++p) {
    const float val = (y[(size_t)perm_i[p] * 64 + c] - fm) * finv;
    si += val > 0.f ? val : 0.f;
  }
  float sj = 0.f;
  const int jb = rowptr_j[n], je = rowptr_j[n + 1];
  for (int p = jb; p < je; ++p) {
    const float val = (y[(size_t)perm_j[p] * 64 + c] - fm) * finv;
    sj += val > 0.f ? val : 0.f;
  }

  const float xv = xn_node[(size_t)n * 64 + c];
  const float a = 0.5f * (si + sj);
  const float d = si - sj;
  float acc = 0.f;
#pragma unroll
  for (int k = 0; k < 64; k++) {
    const float ak = __shfl(a, k);
    const float xk = __shfl(xv, k);
    const float dk = __shfl(d, k);
    acc += WNaT[k * 64 + c] * ak;
    acc += WNbT[k * 64 + c] * xk;
    acc += WNcT[k * 64 + c] * dk;
  }
  const float xn_new = xv + H_COEF * acc;
  if (FINAL) {
    float o = 0.f;
#pragma unroll
    for (int k = 0; k < 64; k++) o += WNclT[k * 64 + c] * __shfl(xn_new, k);
    xn_out[(size_t)c * N + n] = o;
  } else {
    xn_node[(size_t)n * 64 + c] = xn_new;
    float ua = 0.f, va = 0.f;
#pragma unroll
    for (int k = 0; k < 64; k++) {
      const float xk = __shfl(xn_new, k);
      ua += WUTn[k * 64 + c] * xk;
      va += WVTn[k * 64 + c] * xk;
    }
    U[(size_t)n * 64 + c] = ua;
    V[(size_t)n * 64 + c] = va;
  }
}

// ---------------------------------------------------------------------------
extern "C" void kernel_launch(void* const* d_in, const int* in_sizes, int n_in,
                              void* d_out, int out_size, void* d_ws,
                              size_t ws_size, hipStream_t stream) {
  const float* xn_in = (const float*)d_in[0];
  const float* xe_in = (const float*)d_in[1];
  const int* iInd = (const int*)d_in[2];
  const int* jInd = (const int*)d_in[3];
  const float* KNopen = (const float*)d_in[4];
  const float* KEopen = (const float*)d_in[5];
  const float* KNclose = (const float*)d_in[6];
  const float* KEclose = (const float*)d_in[7];
  const float* KE1 = (const float*)d_in[8];
  const float* KE2 = (const float*)d_in[9];
  const float* KE3 = (const float*)d_in[10];
  const float* KN = (const float*)d_in[11];

  const int N = in_sizes[0] / 16;               // 20000
  const int E = in_sizes[2];                    // 320000
  const int nlayer = in_sizes[8] / (64 * 192);  // 4

  float* out = (float*)d_out;
  float* xn_out = out;  // [64][N] feature-major (final)
  // During layers this region holds xe EDGE-major [E][64] (same byte count);
  // final feature-major xe is produced in scratch and memcpy'd here.
  float* xe = out + (size_t)64 * N;

  float* ws = (float*)d_ws;
  float* y = ws;                          // [E][64]; reused as close scratch
  float* U = y + (size_t)64 * E;          // [N][64]
  float* V = U + (size_t)64 * N;          // [N][64]
  float* xn_node = V + (size_t)64 * N;    // [N][64]
  float* WUT = xn_node + (size_t)64 * N;  // nlayer*4096 each
  float* WVT = WUT + (size_t)4096 * nlayer;
  float* WNaT = WVT + (size_t)4096 * nlayer;
  float* WNbT = WNaT + (size_t)4096 * nlayer;
  float* WNcT = WNbT + (size_t)4096 * nlayer;
  float* WNopT = WNcT + (size_t)4096 * nlayer;  // 1024
  float* WNclT = WNopT + 1024;                  // 4096
  double* stat = (double*)(WNclT + 4096);       // nlayer*4 doubles
  int* cnt_i = (int*)(stat + 4 * nlayer);
  int* cnt_j = cnt_i + N;
  int* rowptr_i = cnt_j + N;
  int* cursor_i = rowptr_i + (N + 1);
  int* rowptr_j = cursor_i + N;
  int* cursor_j = rowptr_j + (N + 1);
  int* perm_i = cursor_j + N;
  int* perm_j = perm_i + E;

  const int be = (E + 255) / 256;
  const int bw = (N + 3) / 4;  // wave-per-node kernels
  const double inv_n = 1.0 / (64.0 * (double)E);

  hipMemsetAsync(stat, 0, (size_t)nlayer * 4 * sizeof(double), stream);
  hipMemsetAsync(cnt_i, 0, (size_t)2 * N * sizeof(int), stream);

  prep_weights_kernel<<<(nlayer * 4096 + 255) / 256, 256, 0, stream>>>(
      KE1, KN, KNopen, KNclose, WUT, WVT, WNaT, WNbT, WNcT, WNopT, WNclT,
      nlayer);

  hist_kernel<<<be, 256, 0, stream>>>(iInd, jInd, cnt_i, cnt_j, E);
  scan_kernel<<<1, 1024, 0, stream>>>(cnt_i, cnt_j, rowptr_i, cursor_i,
                                      rowptr_j, cursor_j, N);
  fill_kernel<<<be, 256, 0, stream>>>(iInd, jInd, cursor_i, cursor_j, perm_i,
                                      perm_j, E);

  open_node_uv_kernel<<<bw, 256, 0, stream>>>(WNopT, xn_in, WUT, WVT, xn_node,
                                              U, V, N);

  for (int l = 0; l < nlayer; l++) {
    const float* KE1_l = KE1 + (size_t)l * 64 * 192;
    const float* KE2_l = KE2 + (size_t)l * 64 * 64;
    const float* KE3_l = KE3 + (size_t)l * 64 * 64;
    double* st1 = stat + (size_t)l * 4;
    double* st2 = st1 + 2;
    const bool last = (l == nlayer - 1);

    if (l == 0) {
      edge1_kernel<true><<<be, 256, 0, stream>>>(KE1_l, KEopen, xe_in, xe, U,
                                                 V, iInd, jInd, y, st1, E);
    } else {
      edge1_kernel<false><<<be, 256, 0, stream>>>(KE1_l, KEopen, xe_in, xe, U,
                                                  V, iInd, jInd, y, st1, E);
    }
    edge2_kernel<<<be, 256, 0, stream>>>(KE2_l, y, st1, st2, inv_n, E);
    edge3_kernel<<<be, 256, 0, stream>>>(KE3_l, y, xe, st2, inv_n, E);
    if (last) {
      fused_node_kernel<true><<<bw, 256, 0, stream>>>(
          y, rowptr_i, perm_i, rowptr_j, perm_j, WNaT + (size_t)l * 4096,
          WNbT + (size_t)l * 4096, WNcT + (size_t)l * 4096, WUT, WVT, WNclT,
          xn_node, U, V, xn_out, st2, inv_n, N);
    } else {
      fused_node_kernel<false><<<bw, 256, 0, stream>>>(
          y, rowptr_i, perm_i, rowptr_j, perm_j, WNaT + (size_t)l * 4096,
          WNbT + (size_t)l * 4096, WNcT + (size_t)l * 4096,
          WUT + (size_t)(l + 1) * 4096, WVT + (size_t)(l + 1) * 4096, WNclT,
          xn_node, U, V, xn_out, st2, inv_n, N);
    }
  }

  // close: xe rows -> feature-major into scratch (y, dead), then copy out.
  close_edge_kernel<<<be, 256, 0, stream>>>(KEclose, xe, y, E);
  hipMemcpyAsync(xe, y, (size_t)64 * E * sizeof(float),
                 hipMemcpyDeviceToDevice, stream);
}

// Round 4
// 2300.849 us; speedup vs baseline: 1.2078x; 1.1504x over previous
//
#include <hip/hip_runtime.h>
#include <math.h>

#define H_COEF 0.1f
#define LN_EPS 1e-5

// Baseline-proven LDS tile swizzle for full 64ch x 256edge staging (64 KB):
// idx(c, el) = c*256 + (el ^ c).
__device__ __forceinline__ int lds_idx(int c, int el) {
  return (c << 8) + (el ^ c);
}

// 4 parallel accumulator chains over k (4-way ILP vs 4-cyc FMA dep latency).
// Per-channel summation order (k ascending) identical to baseline ->
// bit-identical results; only cross-channel interleaving changes.
template <int STRIDE>
__device__ __forceinline__ void mm4(const float* __restrict__ Wr,
                                    const float (&x)[64], float (&acc)[4]) {
#pragma unroll
  for (int k = 0; k < 64; k++) {
    const float xk = x[k];
    acc[0] += Wr[0 * STRIDE + k] * xk;
    acc[1] += Wr[1 * STRIDE + k] * xk;
    acc[2] += Wr[2 * STRIDE + k] * xk;
    acc[3] += Wr[3 * STRIDE + k] * xk;
  }
}

// ---------------------------------------------------------------------------
// Block-level (sum, sumsq) reduction -> atomicAdd(double) to global stat[2].
// ---------------------------------------------------------------------------
__device__ __forceinline__ void stat_reduce(float s, float ss, double* stat) {
#pragma unroll
  for (int off = 32; off > 0; off >>= 1) {
    s += __shfl_down(s, off);
    ss += __shfl_down(ss, off);
  }
  __shared__ float bs[8], bss[8];
  const int wid = threadIdx.x >> 6;
  const int lane = threadIdx.x & 63;
  if (lane == 0) { bs[wid] = s; bss[wid] = ss; }
  __syncthreads();
  if (threadIdx.x == 0) {
    float S = 0.f, SS = 0.f;
    const int nw = blockDim.x >> 6;
    for (int w = 0; w < nw; w++) { S += bs[w]; SS += bss[w]; }
    atomicAdd(stat, (double)S);
    atomicAdd(stat + 1, (double)SS);
  }
}

// ---------------------------------------------------------------------------
// Weight prep: transposed (and pre-combined) copies, [k][c] layout.
// ---------------------------------------------------------------------------
__global__ __launch_bounds__(256) void prep_weights_kernel(
    const float* __restrict__ KE1, const float* __restrict__ KN,
    const float* __restrict__ KNopen, const float* __restrict__ KNclose,
    float* __restrict__ WUT, float* __restrict__ WVT, float* __restrict__ WNaT,
    float* __restrict__ WNbT, float* __restrict__ WNcT,
    float* __restrict__ WNopT, float* __restrict__ WNclT, int nlayer) {
  const int idx = blockIdx.x * blockDim.x + threadIdx.x;
  const int total = nlayer * 4096;
  if (idx < total) {
    const int l = idx >> 12;
    const int r = idx & 4095;
    const int k = r >> 6;
    const int c = r & 63;
    const float a = KE1[(size_t)l * 12288 + c * 192 + k];
    const float g = KE1[(size_t)l * 12288 + c * 192 + 128 + k];
    WUT[idx] = 0.5f * a + g;
    WVT[idx] = 0.5f * a - g;
    WNaT[idx] = KN[(size_t)l * 12288 + c * 192 + k];
    WNbT[idx] = KN[(size_t)l * 12288 + c * 192 + 64 + k];
    WNcT[idx] = KN[(size_t)l * 12288 + c * 192 + 128 + k];
  }
  if (idx < 4096) {
    const int k = idx >> 6;
    const int c = idx & 63;
    WNclT[idx] = KNclose[c * 64 + k];
    if (k < 16) WNopT[k * 64 + c] = KNopen[c * 16 + k];
  }
}

// ---------------------------------------------------------------------------
// CSR construction (per launch; indices are fixed inputs).
// ---------------------------------------------------------------------------
__global__ __launch_bounds__(256) void hist_kernel(
    const int* __restrict__ iInd, const int* __restrict__ jInd,
    int* __restrict__ cnt_i, int* __restrict__ cnt_j, int E) {
  const int e = blockIdx.x * blockDim.x + threadIdx.x;
  if (e < E) {
    atomicAdd(&cnt_i[iInd[e]], 1);
    atomicAdd(&cnt_j[jInd[e]], 1);
  }
}

// Packed scan: cnt_i in low 32 bits, cnt_j in high 32 bits (single pass).
__global__ __launch_bounds__(1024) void scan_kernel(
    const int* __restrict__ cnt_i, const int* __restrict__ cnt_j,
    int* __restrict__ rowptr_i, int* __restrict__ cursor_i,
    int* __restrict__ rowptr_j, int* __restrict__ cursor_j, int N) {
  __shared__ unsigned long long carry;
  __shared__ unsigned long long tmp[1024];
  if (threadIdx.x == 0) carry = 0ull;
  __syncthreads();
  for (int base = 0; base < N; base += 1024) {
    const int idx = base + threadIdx.x;
    unsigned long long v = 0ull;
    if (idx < N)
      v = (unsigned long long)(unsigned)cnt_i[idx] |
          ((unsigned long long)(unsigned)cnt_j[idx] << 32);
    tmp[threadIdx.x] = v;
    unsigned long long acc = v;
    __syncthreads();
    for (int off = 1; off < 1024; off <<= 1) {
      const unsigned long long add =
          (threadIdx.x >= (unsigned)off) ? tmp[threadIdx.x - off] : 0ull;
      __syncthreads();
      acc += add;
      tmp[threadIdx.x] = acc;
      __syncthreads();
    }
    const unsigned long long excl = acc - v + carry;
    if (idx < N) {
      const int lo = (int)(excl & 0xffffffffull);
      const int hi = (int)(excl >> 32);
      rowptr_i[idx] = lo;
      cursor_i[idx] = lo;
      rowptr_j[idx] = hi;
      cursor_j[idx] = hi;
    }
    __syncthreads();
    if (threadIdx.x == 1023) carry += tmp[1023];
    __syncthreads();
  }
  if (threadIdx.x == 0) {
    rowptr_i[N] = (int)(carry & 0xffffffffull);
    rowptr_j[N] = (int)(carry >> 32);
  }
}

__global__ __launch_bounds__(256) void fill_kernel(
    const int* __restrict__ iInd, const int* __restrict__ jInd,
    int* __restrict__ cursor_i, int* __restrict__ cursor_j,
    int* __restrict__ perm_i, int* __restrict__ perm_j, int E) {
  const int e = blockIdx.x * blockDim.x + threadIdx.x;
  if (e < E) {
    perm_i[atomicAdd(&cursor_i[iInd[e]], 1)] = e;
    perm_j[atomicAdd(&cursor_j[jInd[e]], 1)] = e;
  }
}

// ---------------------------------------------------------------------------
// Node open fused with layer-0 U/V: one wave per node, lane = channel c.
// ---------------------------------------------------------------------------
__global__ __launch_bounds__(256) void open_node_uv_kernel(
    const float* __restrict__ WNopT, const float* __restrict__ xn_in,
    const float* __restrict__ WUT0, const float* __restrict__ WVT0,
    float* __restrict__ xn_node, float* __restrict__ U, float* __restrict__ V,
    int N) {
  const int n = blockIdx.x * 4 + (threadIdx.x >> 6);
  const int c = threadIdx.x & 63;
  if (n >= N) return;
  const float xv = (c < 16) ? xn_in[(size_t)c * N + n] : 0.f;
  float acc = 0.f;
#pragma unroll
  for (int k = 0; k < 16; k++) acc += WNopT[k * 64 + c] * __shfl(xv, k);
  xn_node[(size_t)n * 64 + c] = acc;
  float ua = 0.f, va = 0.f;
#pragma unroll
  for (int k = 0; k < 64; k++) {
    const float xk = __shfl(acc, k);
    ua += WUT0[k * 64 + c] * xk;
    va += WVT0[k * 64 + c] * xk;
  }
  U[(size_t)n * 64 + c] = ua;
  V[(size_t)n * 64 + c] = va;
}

// ---------------------------------------------------------------------------
// edge1: y[e][:] = U[i(e)][:] + V[j(e)][:] + B1 @ xe[:,e];  stats of y.
// xe is FEATURE-major [64][E] (wave-coalesced strided reads, as baseline).
// FIRST layer computes xe = KEopen @ xe_in in-reg and writes xe (open fused).
// y writes staged via full 64 KB LDS -> complete 256 B rows, coalesced,
// no write amplification (the round-2/3 partial-row staging measured 2x).
// mm4: 4 independent FMA chains per channel group.
// ---------------------------------------------------------------------------
template <bool FIRST>
__global__ __launch_bounds__(256) void edge1_kernel(
    const float* __restrict__ KE1_l, const float* __restrict__ KEopen,
    const float* __restrict__ xe_in, float* __restrict__ xe,
    const float* __restrict__ U, const float* __restrict__ V,
    const int* __restrict__ iInd, const int* __restrict__ jInd,
    float* __restrict__ y, double* __restrict__ stat, int E) {
  __shared__ float sbuf[16384];
  const int t = threadIdx.x;
  const int base = blockIdx.x * 256;
  const int e = base + t;
  const bool full = (base + 256 <= E);
  float s = 0.f, ss = 0.f;
  float xcol[64];
  if (e < E) {
    if (FIRST) {
      float xin[16];
#pragma unroll
      for (int k = 0; k < 16; k++) xin[k] = xe_in[(size_t)k * E + e];
#pragma unroll
      for (int cc = 0; cc < 64; cc++) {
        float a = 0.f;
#pragma unroll
        for (int k = 0; k < 16; k++) a += KEopen[cc * 16 + k] * xin[k];
        xcol[cc] = a;
        xe[(size_t)cc * E + e] = a;  // coalesced feature-major store
      }
    } else {
#pragma unroll
      for (int k = 0; k < 64; k++) xcol[k] = xe[(size_t)k * E + e];
    }
    const int vi = iInd[e];
    const int vj = jInd[e];
    const float4* Up = (const float4*)(U + (size_t)vi * 64);
    const float4* Vp = (const float4*)(V + (size_t)vj * 64);
#pragma unroll
    for (int cg = 0; cg < 16; cg++) {
      const float4 uq = Up[cg];
      const float4 vq = Vp[cg];
      float acc[4] = {uq.x + vq.x, uq.y + vq.y, uq.z + vq.z, uq.w + vq.w};
      mm4<192>(KE1_l + (cg * 4) * 192 + 64, xcol, acc);
#pragma unroll
      for (int u = 0; u < 4; u++) {
        const float a = acc[u];
        s += a;
        ss += a * a;
        if (full) sbuf[lds_idx(cg * 4 + u, t)] = a;
        else y[(size_t)e * 64 + cg * 4 + u] = a;
      }
    }
  }
  if (full) {
    __syncthreads();
    float4* dst = (float4*)(y + (size_t)base * 64);
#pragma unroll
    for (int it = 0; it < 16; it++) {
      const int f4 = t + it * 256;
      const int el = f4 >> 4;
      const int cb = (f4 & 15) << 2;
      float4 r;
      r.x = sbuf[lds_idx(cb + 0, el)];
      r.y = sbuf[lds_idx(cb + 1, el)];
      r.z = sbuf[lds_idx(cb + 2, el)];
      r.w = sbuf[lds_idx(cb + 3, el)];
      dst[f4] = r;
    }
  }
  stat_reduce(s, ss, stat);
}

// ---------------------------------------------------------------------------
// edge2: t = relu(ln(y row)); y row <- KE2 @ t (in place); stats of new y.
// Baseline structure: coalesced read-stage through LDS, per-thread LN from
// LDS, mm4 matmul back into LDS, coalesced write-out.
// ---------------------------------------------------------------------------
__global__ __launch_bounds__(256) void edge2_kernel(
    const float* __restrict__ W, float* __restrict__ y,
    const double* __restrict__ statIn, double* __restrict__ statOut,
    double inv_n, int E) {
  __shared__ float sbuf[16384];
  const int t = threadIdx.x;
  const int base = blockIdx.x * 256;
  const int e = base + t;
  const bool full = (base + 256 <= E);
  float s = 0.f, ss = 0.f;
  if (full) {
    const float4* src = (const float4*)(y + (size_t)base * 64);
#pragma unroll
    for (int it = 0; it < 16; it++) {
      const int f4 = t + it * 256;
      const int el = f4 >> 4;
      const int cb = (f4 & 15) << 2;
      const float4 r = src[f4];
      sbuf[lds_idx(cb + 0, el)] = r.x;
      sbuf[lds_idx(cb + 1, el)] = r.y;
      sbuf[lds_idx(cb + 2, el)] = r.z;
      sbuf[lds_idx(cb + 3, el)] = r.w;
    }
    __syncthreads();
  }
  if (e < E) {
    const double m = statIn[0] * inv_n;
    const double v = statIn[1] * inv_n - m * m;
    const float fm = (float)m;
    const float finv = (float)(1.0 / sqrt(v + LN_EPS));
    float tv[64];
    if (full) {
#pragma unroll
      for (int c = 0; c < 64; c++) {
        const float val = (sbuf[lds_idx(c, t)] - fm) * finv;
        tv[c] = val > 0.f ? val : 0.f;
      }
    } else {
#pragma unroll
      for (int c = 0; c < 64; c++) {
        const float val = (y[(size_t)e * 64 + c] - fm) * finv;
        tv[c] = val > 0.f ? val : 0.f;
      }
    }
#pragma unroll
    for (int cg = 0; cg < 16; cg++) {
      float acc[4] = {0.f, 0.f, 0.f, 0.f};
      mm4<64>(W + (cg * 4) * 64, tv, acc);
#pragma unroll
      for (int u = 0; u < 4; u++) {
        const float a = acc[u];
        s += a;
        ss += a * a;
        if (full) sbuf[lds_idx(cg * 4 + u, t)] = a;
        else y[(size_t)e * 64 + cg * 4 + u] = a;
      }
    }
  }
  if (full) {
    __syncthreads();
    float4* dst = (float4*)(y + (size_t)base * 64);
#pragma unroll
    for (int it = 0; it < 16; it++) {
      const int f4 = t + it * 256;
      const int el = f4 >> 4;
      const int cb = (f4 & 15) << 2;
      float4 r;
      r.x = sbuf[lds_idx(cb + 0, el)];
      r.y = sbuf[lds_idx(cb + 1, el)];
      r.z = sbuf[lds_idx(cb + 2, el)];
      r.w = sbuf[lds_idx(cb + 3, el)];
      dst[f4] = r;
    }
  }
  stat_reduce(s, ss, statOut);
}

// ---------------------------------------------------------------------------
// edge3: t2 = relu(ln(y row));  xe col += H * (KE3 @ t2).  y unchanged.
// Feature-major xe RMW: per-thread strided = per-wave coalesced (baseline).
// ---------------------------------------------------------------------------
__global__ __launch_bounds__(256) void edge3_kernel(
    const float* __restrict__ W, const float* __restrict__ y,
    float* __restrict__ xe, const double* __restrict__ statIn, double inv_n,
    int E) {
  const int e = blockIdx.x * blockDim.x + threadIdx.x;
  if (e >= E) return;
  const double m = statIn[0] * inv_n;
  const double v = statIn[1] * inv_n - m * m;
  const float fm = (float)m;
  const float finv = (float)(1.0 / sqrt(v + LN_EPS));
  float tv[64];
  const float4* yrow = (const float4*)(y + (size_t)e * 64);
#pragma unroll
  for (int q = 0; q < 16; q++) {
    const float4 r = yrow[q];
    const float* rp = (const float*)&r;
#pragma unroll
    for (int u = 0; u < 4; u++) {
      const float val = (rp[u] - fm) * finv;
      tv[q * 4 + u] = val > 0.f ? val : 0.f;
    }
  }
#pragma unroll
  for (int cg = 0; cg < 16; cg++) {
    float acc[4] = {0.f, 0.f, 0.f, 0.f};
    mm4<64>(W + (cg * 4) * 64, tv, acc);
#pragma unroll
    for (int u = 0; u < 4; u++) {
      const size_t off = (size_t)(cg * 4 + u) * E + e;
      xe[off] += H_COEF * acc[u];
    }
  }
}

// ---------------------------------------------------------------------------
// Edge close (out-of-loop): x col <- KEclose @ x col, in place (feature-major,
// per-thread read-all-then-write-all, as baseline) with mm4.
// ---------------------------------------------------------------------------
__global__ __launch_bounds__(256) void close_edge_kernel(
    const float* __restrict__ W, float* __restrict__ x, int M) {
  const int e = blockIdx.x * blockDim.x + threadIdx.x;
  if (e >= M) return;
  float xv[64];
#pragma unroll
  for (int k = 0; k < 64; k++) xv[k] = x[(size_t)k * M + e];
#pragma unroll
  for (int cg = 0; cg < 16; cg++) {
    float acc[4] = {0.f, 0.f, 0.f, 0.f};
    mm4<64>(W + (cg * 4) * 64, xv, acc);
#pragma unroll
    for (int u = 0; u < 4; u++)
      x[(size_t)(cg * 4 + u) * M + e] = acc[u];
  }
}

// ---------------------------------------------------------------------------
// fused node update: one wave per node; lane = channel c.
// Non-final layers additionally emit next layer's U,V (uv fused).
// Final layer applies KNclose and writes xn output (close_node fused).
// ---------------------------------------------------------------------------
template <bool FINAL>
__global__ __launch_bounds__(256) void fused_node_kernel(
    const float* __restrict__ y, const int* __restrict__ rowptr_i,
    const int* __restrict__ perm_i, const int* __restrict__ rowptr_j,
    const int* __restrict__ perm_j, const float* __restrict__ WNaT,
    const float* __restrict__ WNbT, const float* __restrict__ WNcT,
    const float* __restrict__ WUTn, const float* __restrict__ WVTn,
    const float* __restrict__ WNclT, float* __restrict__ xn_node,
    float* __restrict__ U, float* __restrict__ V, float* __restrict__ xn_out,
    const double* __restrict__ statIn, double inv_n, int N) {
  const int n = blockIdx.x * 4 + (threadIdx.x >> 6);
  const int c = threadIdx.x & 63;
  if (n >= N) return;
  const double m = statIn[0] * inv_n;
  const double v = statIn[1] * inv_n - m * m;
  const float fm = (float)m;
  const float finv = (float)(1.0 / sqrt(v + LN_EPS));

  float si = 0.f;
  const int ib = rowptr_i[n], ie = rowptr_i[n + 1];
  for (int p = ib; p < ie; ++p) {
    const float val = (y[(size_t)perm_i[p] * 64 + c] - fm) * finv;
    si += val > 0.f ? val : 0.f;
  }
  float sj = 0.f;
  const int jb = rowptr_j[n], je = rowptr_j[n + 1];
  for (int p = jb; p < je; ++p) {
    const float val = (y[(size_t)perm_j[p] * 64 + c] - fm) * finv;
    sj += val > 0.f ? val : 0.f;
  }

  const float xv = xn_node[(size_t)n * 64 + c];
  const float a = 0.5f * (si + sj);
  const float d = si - sj;
  float acc = 0.f;
#pragma unroll
  for (int k = 0; k < 64; k++) {
    const float ak = __shfl(a, k);
    const float xk = __shfl(xv, k);
    const float dk = __shfl(d, k);
    acc += WNaT[k * 64 + c] * ak;
    acc += WNbT[k * 64 + c] * xk;
    acc += WNcT[k * 64 + c] * dk;
  }
  const float xn_new = xv + H_COEF * acc;
  if (FINAL) {
    float o = 0.f;
#pragma unroll
    for (int k = 0; k < 64; k++) o += WNclT[k * 64 + c] * __shfl(xn_new, k);
    xn_out[(size_t)c * N + n] = o;
  } else {
    xn_node[(size_t)n * 64 + c] = xn_new;
    float ua = 0.f, va = 0.f;
#pragma unroll
    for (int k = 0; k < 64; k++) {
      const float xk = __shfl(xn_new, k);
      ua += WUTn[k * 64 + c] * xk;
      va += WVTn[k * 64 + c] * xk;
    }
    U[(size_t)n * 64 + c] = ua;
    V[(size_t)n * 64 + c] = va;
  }
}

// ---------------------------------------------------------------------------
extern "C" void kernel_launch(void* const* d_in, const int* in_sizes, int n_in,
                              void* d_out, int out_size, void* d_ws,
                              size_t ws_size, hipStream_t stream) {
  const float* xn_in = (const float*)d_in[0];
  const float* xe_in = (const float*)d_in[1];
  const int* iInd = (const int*)d_in[2];
  const int* jInd = (const int*)d_in[3];
  const float* KNopen = (const float*)d_in[4];
  const float* KEopen = (const float*)d_in[5];
  const float* KNclose = (const float*)d_in[6];
  const float* KEclose = (const float*)d_in[7];
  const float* KE1 = (const float*)d_in[8];
  const float* KE2 = (const float*)d_in[9];
  const float* KE3 = (const float*)d_in[10];
  const float* KN = (const float*)d_in[11];

  const int N = in_sizes[0] / 16;               // 20000
  const int E = in_sizes[2];                    // 320000
  const int nlayer = in_sizes[8] / (64 * 192);  // 4

  float* out = (float*)d_out;
  float* xn_out = out;               // [64][N] feature-major (final)
  float* xe = out + (size_t)64 * N;  // [64][E] feature-major, in-place

  float* ws = (float*)d_ws;
  float* y = ws;                          // [E][64]
  float* U = y + (size_t)64 * E;          // [N][64]
  float* V = U + (size_t)64 * N;          // [N][64]
  float* xn_node = V + (size_t)64 * N;    // [N][64]
  float* WUT = xn_node + (size_t)64 * N;  // nlayer*4096 each
  float* WVT = WUT + (size_t)4096 * nlayer;
  float* WNaT = WVT + (size_t)4096 * nlayer;
  float* WNbT = WNaT + (size_t)4096 * nlayer;
  float* WNcT = WNbT + (size_t)4096 * nlayer;
  float* WNopT = WNcT + (size_t)4096 * nlayer;  // 1024
  float* WNclT = WNopT + 1024;                  // 4096
  double* stat = (double*)(WNclT + 4096);       // nlayer*4 doubles
  int* cnt_i = (int*)(stat + 4 * nlayer);
  int* cnt_j = cnt_i + N;
  int* rowptr_i = cnt_j + N;
  int* cursor_i = rowptr_i + (N + 1);
  int* rowptr_j = cursor_i + N;
  int* cursor_j = rowptr_j + (N + 1);
  int* perm_i = cursor_j + N;
  int* perm_j = perm_i + E;

  const int be = (E + 255) / 256;
  const int bw = (N + 3) / 4;  // wave-per-node kernels
  const double inv_n = 1.0 / (64.0 * (double)E);

  hipMemsetAsync(stat, 0, (size_t)nlayer * 4 * sizeof(double), stream);
  hipMemsetAsync(cnt_i, 0, (size_t)2 * N * sizeof(int), stream);

  prep_weights_kernel<<<(nlayer * 4096 + 255) / 256, 256, 0, stream>>>(
      KE1, KN, KNopen, KNclose, WUT, WVT, WNaT, WNbT, WNcT, WNopT, WNclT,
      nlayer);

  hist_kernel<<<be, 256, 0, stream>>>(iInd, jInd, cnt_i, cnt_j, E);
  scan_kernel<<<1, 1024, 0, stream>>>(cnt_i, cnt_j, rowptr_i, cursor_i,
                                      rowptr_j, cursor_j, N);
  fill_kernel<<<be, 256, 0, stream>>>(iInd, jInd, cursor_i, cursor_j, perm_i,
                                      perm_j, E);

  open_node_uv_kernel<<<bw, 256, 0, stream>>>(WNopT, xn_in, WUT, WVT, xn_node,
                                              U, V, N);

  for (int l = 0; l < nlayer; l++) {
    const float* KE1_l = KE1 + (size_t)l * 64 * 192;
    const float* KE2_l = KE2 + (size_t)l * 64 * 64;
    const float* KE3_l = KE3 + (size_t)l * 64 * 64;
    double* st1 = stat + (size_t)l * 4;
    double* st2 = st1 + 2;
    const bool last = (l == nlayer - 1);

    if (l == 0) {
      edge1_kernel<true><<<be, 256, 0, stream>>>(KE1_l, KEopen, xe_in, xe, U,
                                                 V, iInd, jInd, y, st1, E);
    } else {
      edge1_kernel<false><<<be, 256, 0, stream>>>(KE1_l, KEopen, xe_in, xe, U,
                                                  V, iInd, jInd, y, st1, E);
    }
    edge2_kernel<<<be, 256, 0, stream>>>(KE2_l, y, st1, st2, inv_n, E);
    edge3_kernel<<<be, 256, 0, stream>>>(KE3_l, y, xe, st2, inv_n, E);
    if (last) {
      fused_node_kernel<true><<<bw, 256, 0, stream>>>(
          y, rowptr_i, perm_i, rowptr_j, perm_j, WNaT + (size_t)l * 4096,
          WNbT + (size_t)l * 4096, WNcT + (size_t)l * 4096, WUT, WVT, WNclT,
          xn_node, U, V, xn_out, st2, inv_n, N);
    } else {
      fused_node_kernel<false><<<bw, 256, 0, stream>>>(
          y, rowptr_i, perm_i, rowptr_j, perm_j, WNaT + (size_t)l * 4096,
          WNbT + (size_t)l * 4096, WNcT + (size_t)l * 4096,
          WUT + (size_t)(l + 1) * 4096, WVT + (size_t)(l + 1) * 4096, WNclT,
          xn_node, U, V, xn_out, st2, inv_n, N);
    }
  }

  close_edge_kernel<<<be, 256, 0, stream>>>(KEclose, xe, E);
}